// Round 12
// baseline (2207.100 us; speedup 1.0000x reference)
//
#include <hip/hip_runtime.h>
#include <hip/hip_bf16.h>
#include <hip/hip_fp16.h>
#include <math.h>

#define HID 64

union HU { __half h; unsigned short u; };
__device__ inline unsigned short f2h(float f) { HU x; x.h = __float2half(f); return x.u; }
__device__ inline float h2f(unsigned short u) { HU x; x.u = u; return __half2float(x.h); }

// ---------------- CSR build ----------------

__global__ void count_kernel(const int* __restrict__ dst, int* __restrict__ cnt, int E, int N) {
    int e = blockIdx.x * blockDim.x + threadIdx.x;
    if (e < E) {
        int d = dst[e];
        if ((unsigned)d < (unsigned)N) atomicAdd(&cnt[d], 1);
    }
}

__global__ void dinv_kernel(const int* __restrict__ cnt, float* __restrict__ dinv, int n) {
    int i = blockIdx.x * blockDim.x + threadIdx.x;
    if (i < n) {
        float deg = (float)(cnt[i] + 1);   // +1 self loop
        dinv[i] = rsqrtf(deg);
    }
}

// two-level scan
__global__ __launch_bounds__(1024) void scanA_kernel(const int* __restrict__ cnt,
        int* __restrict__ offs, int* __restrict__ bsum, int n) {
    __shared__ int buf[1024];
    int tid = threadIdx.x;
    int i = blockIdx.x * 1024 + tid;
    int v = (i < n) ? cnt[i] : 0;
    buf[tid] = v;
    __syncthreads();
    for (int off = 1; off < 1024; off <<= 1) {
        int t = (tid >= off) ? buf[tid - off] : 0;
        __syncthreads();
        buf[tid] += t;
        __syncthreads();
    }
    if (i < n) offs[i] = buf[tid] - v;
    if (tid == 1023) bsum[blockIdx.x] = buf[1023];
}

__global__ __launch_bounds__(1024) void scanB_kernel(int* __restrict__ bsum, int nb) {
    __shared__ int buf[1024];
    int tid = threadIdx.x;
    int v = (tid < nb) ? bsum[tid] : 0;
    buf[tid] = v;
    __syncthreads();
    for (int off = 1; off < 1024; off <<= 1) {
        int t = (tid >= off) ? buf[tid - off] : 0;
        __syncthreads();
        buf[tid] += t;
        __syncthreads();
    }
    if (tid < nb) bsum[tid] = buf[tid] - v;
    if (tid == nb - 1) bsum[nb] = buf[tid];
}

__global__ __launch_bounds__(1024) void scanC_kernel(int* __restrict__ offs,
        const int* __restrict__ bsum, int n, int nb) {
    int i = blockIdx.x * 1024 + threadIdx.x;
    if (i < n) offs[i] += bsum[i >> 10];
    if (i == 0) offs[n] = bsum[nb];
}

// packed edge record: {src, norm}
__global__ void fill_kernel(const int* __restrict__ src, const int* __restrict__ dst,
                            const int* __restrict__ offs, int* __restrict__ cursor,
                            const float* __restrict__ dinv,
                            int2* __restrict__ pack, int E, int N) {
    int e = blockIdx.x * blockDim.x + threadIdx.x;
    if (e < E) {
        int s = src[e], d = dst[e];
        if ((unsigned)s < (unsigned)N && (unsigned)d < (unsigned)N) {
            int pos = atomicAdd(&cursor[d], 1);
            int j = offs[d] + pos;
            if ((unsigned)j < (unsigned)E)
                pack[j] = make_int2(s, __float_as_int(dinv[s] * dinv[d]));
        }
    }
}

// ---------------- lin1: h0 = relu(x @ W1 + b1) ----------------
// BM=32 -> 1563 blocks (~6/CU) to fix grid-capped occupancy.
// register-prefetch double buffer; outputs fp32 x0 + fp16 h0.

__global__ __launch_bounds__(256) void lin1_kernel(const float* __restrict__ x,
        const float* __restrict__ W, const float* __restrict__ b,
        float* __restrict__ out32, unsigned short* __restrict__ out16, int n) {
    const int BM = 32, BK = 32;
    __shared__ float As[BM][BK + 1];
    __shared__ float Ws[BK][64];
    int tid = threadIdx.x;
    int row0 = blockIdx.x * BM;
    int tx = tid & 15, ty = tid >> 4;     // 16x16 threads, each 2 rows x 4 cols
    float acc[2][4] = {};

    int ar = tid >> 3, ac4 = tid & 7;     // A: 1 float4/thread
    int wr = tid >> 4, wc4 = tid & 15;    // W: 2 float4/thread (rows wr, wr+16)
    float4 a_pf, w_pf0, w_pf1;

    {   // prologue prefetch k0 = 0
        int row = row0 + ar;
        a_pf = make_float4(0.f, 0.f, 0.f, 0.f);
        if (row < n) a_pf = *(const float4*)&x[(size_t)row * 512 + ac4 * 4];
        w_pf0 = *(const float4*)&W[(size_t)wr * 64 + wc4 * 4];
        w_pf1 = *(const float4*)&W[(size_t)(wr + 16) * 64 + wc4 * 4];
    }

    for (int k0 = 0; k0 < 512; k0 += BK) {
        As[ar][ac4 * 4 + 0] = a_pf.x;
        As[ar][ac4 * 4 + 1] = a_pf.y;
        As[ar][ac4 * 4 + 2] = a_pf.z;
        As[ar][ac4 * 4 + 3] = a_pf.w;
        *(float4*)&Ws[wr][wc4 * 4] = w_pf0;
        *(float4*)&Ws[wr + 16][wc4 * 4] = w_pf1;
        __syncthreads();
        int k1 = k0 + BK;
        if (k1 < 512) {
            int row = row0 + ar;
            a_pf = make_float4(0.f, 0.f, 0.f, 0.f);
            if (row < n) a_pf = *(const float4*)&x[(size_t)row * 512 + k1 + ac4 * 4];
            w_pf0 = *(const float4*)&W[(size_t)(k1 + wr) * 64 + wc4 * 4];
            w_pf1 = *(const float4*)&W[(size_t)(k1 + wr + 16) * 64 + wc4 * 4];
        }
        #pragma unroll
        for (int kk = 0; kk < BK; kk++) {
            float a0 = As[ty * 2 + 0][kk];
            float a1 = As[ty * 2 + 1][kk];
            float4 w = *(float4*)&Ws[kk][tx * 4];
            acc[0][0] += a0 * w.x; acc[0][1] += a0 * w.y; acc[0][2] += a0 * w.z; acc[0][3] += a0 * w.w;
            acc[1][0] += a1 * w.x; acc[1][1] += a1 * w.y; acc[1][2] += a1 * w.z; acc[1][3] += a1 * w.w;
        }
        __syncthreads();
    }
    #pragma unroll
    for (int i = 0; i < 2; i++) {
        int row = row0 + ty * 2 + i;
        if (row < n) {
            #pragma unroll
            for (int j = 0; j < 4; j++) {
                int col = tx * 4 + j;
                float v = fmaxf(acc[i][j] + b[col], 0.f);
                out32[(size_t)row * 64 + col] = v;
                out16[(size_t)row * 64 + col] = f2h(v);
            }
        }
    }
}

// ---------------- fused GCNII layer ----------------
// 4 waves/block, 8 nodes/wave (8 groups x 8 lanes, uint4 = 8 fp16 per lane).
// W' = beta*W + (1-beta)*I staged in LDS: y = relu(z @ W') -- no epilogue z re-read.
// Gather 4x unroll -> 32 rows in flight per wave.

__global__ __launch_bounds__(256) void layer_kernel(
        const uint4* __restrict__ h16, const float4* __restrict__ x04,
        unsigned short* __restrict__ h_out,
        const int* __restrict__ rowptr, const int2* __restrict__ pack,
        const float* __restrict__ dinv,
        const float* __restrict__ W, float beta, int n) {
    __shared__ float Wsh[HID * HID];          // 16 KB: W' = beta*W + (1-beta)*I
    __shared__ float zt[4][HID][8];           // 8 KB: [wave][k][node]
    int tid = threadIdx.x;
    float omb = 1.0f - beta;
    for (int i = tid; i < HID * HID; i += 256) {
        int k = i >> 6, cc = i & 63;
        Wsh[i] = beta * W[i] + ((k == cc) ? omb : 0.f);
    }
    __syncthreads();
    int lane = tid & 63, wave = tid >> 6;
    int g = lane >> 3;        // node within wave (0..7)
    int c = lane & 7;         // uint4 slot = features c*8 .. c*8+7

#define UNPACK_ACC(v, nv)                                              \
    { float2 q;                                                        \
      q = __half22float2(*(__half2*)&(v).x); acc[0] += (nv) * q.x; acc[1] += (nv) * q.y; \
      q = __half22float2(*(__half2*)&(v).y); acc[2] += (nv) * q.x; acc[3] += (nv) * q.y; \
      q = __half22float2(*(__half2*)&(v).z); acc[4] += (nv) * q.x; acc[5] += (nv) * q.y; \
      q = __half22float2(*(__half2*)&(v).w); acc[6] += (nv) * q.x; acc[7] += (nv) * q.y; }

    for (int base = (blockIdx.x * 4 + wave) * 8; base < n; base += gridDim.x * 32) {
        // ---- phase 1: gather + x0 residual (group g owns node base+g) ----
        int node = base + g;
        float acc[8] = {0.f, 0.f, 0.f, 0.f, 0.f, 0.f, 0.f, 0.f};
        if (node < n) {
            float di = dinv[node];
            float d2 = di * di;
            uint4 sv = h16[(size_t)node * 8 + c];
            UNPACK_ACC(sv, d2);
            int e0 = rowptr[node];
            int deg = rowptr[node + 1] - e0;
            int e = 0;
            for (; e + 4 <= deg; e += 4) {        // 4 edges x 8 groups = 32 rows in flight
                int2 p0 = pack[e0 + e + 0];
                int2 p1 = pack[e0 + e + 1];
                int2 p2 = pack[e0 + e + 2];
                int2 p3 = pack[e0 + e + 3];
                uint4 v0 = h16[(size_t)p0.x * 8 + c];
                uint4 v1 = h16[(size_t)p1.x * 8 + c];
                uint4 v2 = h16[(size_t)p2.x * 8 + c];
                uint4 v3 = h16[(size_t)p3.x * 8 + c];
                float n0 = __int_as_float(p0.y), n1 = __int_as_float(p1.y);
                float n2 = __int_as_float(p2.y), n3 = __int_as_float(p3.y);
                UNPACK_ACC(v0, n0);
                UNPACK_ACC(v1, n1);
                UNPACK_ACC(v2, n2);
                UNPACK_ACC(v3, n3);
            }
            for (; e < deg; e++) {
                int2 p = pack[e0 + e];
                uint4 v = h16[(size_t)p.x * 8 + c];
                float nv = __int_as_float(p.y);
                UNPACK_ACC(v, nv);
            }
            // z = 0.5*agg + 0.5*x0  (ALPHA = 0.5)
            float4 xa = x04[(size_t)node * 16 + 2 * c];
            float4 xb = x04[(size_t)node * 16 + 2 * c + 1];
            acc[0] = 0.5f * acc[0] + 0.5f * xa.x;
            acc[1] = 0.5f * acc[1] + 0.5f * xa.y;
            acc[2] = 0.5f * acc[2] + 0.5f * xa.z;
            acc[3] = 0.5f * acc[3] + 0.5f * xa.w;
            acc[4] = 0.5f * acc[4] + 0.5f * xb.x;
            acc[5] = 0.5f * acc[5] + 0.5f * xb.y;
            acc[6] = 0.5f * acc[6] + 0.5f * xb.z;
            acc[7] = 0.5f * acc[7] + 0.5f * xb.w;
        }
        // ---- transpose z into zt[k][node] (wave-internal, DS in program order) ----
        #pragma unroll
        for (int j = 0; j < 8; j++)
            zt[wave][c * 8 + j][g] = acc[j];
        // ---- phase 2: y = z @ W' for 8 nodes, lane = output feature ----
        float mv[8] = {0.f, 0.f, 0.f, 0.f, 0.f, 0.f, 0.f, 0.f};
        #pragma unroll 4
        for (int k = 0; k < HID; k++) {
            float4 zA = *(float4*)&zt[wave][k][0];   // broadcast
            float4 zB = *(float4*)&zt[wave][k][4];   // broadcast
            float wk = Wsh[k * HID + lane];          // conflict-free
            mv[0] += zA.x * wk; mv[1] += zA.y * wk;
            mv[2] += zA.z * wk; mv[3] += zA.w * wk;
            mv[4] += zB.x * wk; mv[5] += zB.y * wk;
            mv[6] += zB.z * wk; mv[7] += zB.w * wk;
        }
        // ---- epilogue: relu + store (no z re-read needed: identity folded into W') ----
        #pragma unroll
        for (int j = 0; j < 8; j++) {
            int row = base + j;
            if (row < n)
                h_out[(size_t)row * HID + lane] = f2h(fmaxf(mv[j], 0.f));
        }
    }
#undef UNPACK_ACC
}

// ---------------- lin2 + log_softmax ----------------

__global__ __launch_bounds__(256) void out_kernel(const unsigned short* __restrict__ h,
        const float* __restrict__ W2, const float* __restrict__ b2,
        float* __restrict__ out, int n) {
    __shared__ float W2s[64 * 40];
    alignas(16) __shared__ float hs[4][64];
    int tid = threadIdx.x;
    for (int i = tid; i < 64 * 40; i += 256) W2s[i] = W2[i];
    __syncthreads();
    int lane = tid & 63, wave = tid >> 6;
    int c = (lane < 40) ? lane : 0;
    float wc[64];
    #pragma unroll
    for (int k = 0; k < 64; k++) wc[k] = W2s[k * 40 + c];
    float bias = b2[c];
    for (int i = blockIdx.x * 4 + wave; i < n; i += gridDim.x * 4) {
        hs[wave][lane] = h2f(h[(size_t)i * 64 + lane]);
        float o = bias;
        #pragma unroll
        for (int k4 = 0; k4 < 16; k4++) {
            float4 hb = *(float4*)&hs[wave][k4 * 4];
            o += hb.x * wc[k4 * 4 + 0] + hb.y * wc[k4 * 4 + 1]
               + hb.z * wc[k4 * 4 + 2] + hb.w * wc[k4 * 4 + 3];
        }
        float val = (lane < 40) ? o : -INFINITY;
        float m = val;
        #pragma unroll
        for (int d = 1; d < 64; d <<= 1) m = fmaxf(m, __shfl_xor(m, d, 64));
        float e = (lane < 40) ? expf(o - m) : 0.f;
        float s = e;
        #pragma unroll
        for (int d = 1; d < 64; d <<= 1) s += __shfl_xor(s, d, 64);
        if (lane < 40) out[(size_t)i * 40 + lane] = (o - m) - logf(s);
    }
}

__global__ void zero_out_kernel(float* __restrict__ out, int n) {
    int i = blockIdx.x * blockDim.x + threadIdx.x;
    if (i < n) out[i] = 0.f;
}

// ---------------- launcher ----------------

extern "C" void kernel_launch(void* const* d_in, const int* in_sizes, int n_in,
                              void* d_out, int out_size, void* d_ws, size_t ws_size,
                              hipStream_t stream) {
    const float* x    = (const float*)d_in[0];
    const int*   ei   = (const int*)d_in[1];     // int32
    const float* W1   = (const float*)d_in[2];
    const float* b1   = (const float*)d_in[3];
    const float* Wc   = (const float*)d_in[4];
    const float* W2   = (const float*)d_in[5];
    const float* b2   = (const float*)d_in[6];
    float* outp = (float*)d_out;

    const int N = in_sizes[0] / 512;         // 50000
    const int E = in_sizes[1] / 2;           // 800000
    const int L = in_sizes[4] / (HID * HID); // 64

    const int* src = ei;
    const int* dst = ei + E;
    const int NB_SCAN = (N + 1023) / 1024;   // 49

    size_t need = (size_t)N * HID * 4                 // x0b fp32
                + (size_t)N * HID * 2 * 2             // hA16, hB16
                + ((size_t)N * 3 + (N + 1) + (NB_SCAN + 1)) * 4
                + (size_t)E * 8;
    if (ws_size < need) {
        zero_out_kernel<<<(out_size + 255) / 256, 256, 0, stream>>>(outp, out_size);
        return;
    }
    char* p = (char*)d_ws;
    float* x0b  = (float*)p;               p += (size_t)N * HID * 4;
    unsigned short* hA16 = (unsigned short*)p;  p += (size_t)N * HID * 2;
    unsigned short* hB16 = (unsigned short*)p;  p += (size_t)N * HID * 2;
    float* dinv = (float*)p;               p += (size_t)N * 4;
    int2*  pack = (int2*)p;                p += (size_t)E * 8;
    int*   cnt  = (int*)p;                 p += (size_t)N * 4;
    int*   offs = (int*)p;                 p += (size_t)(N + 1) * 4;
    int*   cursor = (int*)p;               p += (size_t)N * 4;
    int*   bsum = (int*)p;                 p += (size_t)(NB_SCAN + 1) * 4;

    hipMemsetAsync(cnt, 0, (size_t)N * 4, stream);
    hipMemsetAsync(cursor, 0, (size_t)N * 4, stream);

    count_kernel<<<(E + 255) / 256, 256, 0, stream>>>(dst, cnt, E, N);
    dinv_kernel<<<(N + 255) / 256, 256, 0, stream>>>(cnt, dinv, N);
    scanA_kernel<<<NB_SCAN, 1024, 0, stream>>>(cnt, offs, bsum, N);
    scanB_kernel<<<1, 1024, 0, stream>>>(bsum, NB_SCAN);
    scanC_kernel<<<NB_SCAN, 1024, 0, stream>>>(offs, bsum, N, NB_SCAN);
    fill_kernel<<<(E + 255) / 256, 256, 0, stream>>>(src, dst, offs, cursor, dinv,
                                                     pack, E, N);

    lin1_kernel<<<(N + 31) / 32, 256, 0, stream>>>(x, W1, b1, x0b, hA16, N);

    // 32 nodes per block -> 1563 blocks (~6/CU)
    int nblocks = (N + 31) / 32;
    unsigned short* cur_in = hA16;
    unsigned short* cur_out = hB16;
    for (int l = 0; l < L; l++) {
        float beta = log1pf(1.0f / (float)(l + 1));
        layer_kernel<<<nblocks, 256, 0, stream>>>((const uint4*)cur_in, (const float4*)x0b,
                                                  cur_out, offs, pack, dinv,
                                                  Wc + (size_t)l * HID * HID, beta, N);
        unsigned short* nxt = cur_in;
        cur_in = cur_out;
        cur_out = nxt;
    }

    out_kernel<<<1024, 256, 0, stream>>>(cur_in, W2, b2, outp, N);
}

// Round 13
// 2169.851 us; speedup vs baseline: 1.0172x; 1.0172x over previous
//
#include <hip/hip_runtime.h>
#include <hip/hip_bf16.h>
#include <hip/hip_fp16.h>
#include <math.h>

#define HID 64
#define NWIN 7        // source windows: 8192 nodes x 128B = 1MB each (< 4MB per-XCD L2)
#define WSHIFT 13

union HU { __half h; unsigned short u; };
__device__ inline unsigned short f2h(float f) { HU x; x.h = __float2half(f); return x.u; }
__device__ inline float h2f(unsigned short u) { HU x; x.u = u; return __half2float(x.h); }

// ---------------- CSR build (windowed) ----------------

__global__ void count_kernel(const int* __restrict__ src, const int* __restrict__ dst,
                             int* __restrict__ cnt, int* __restrict__ cntw, int E, int N) {
    int e = blockIdx.x * blockDim.x + threadIdx.x;
    if (e < E) {
        int s = src[e], d = dst[e];
        if ((unsigned)s < (unsigned)N && (unsigned)d < (unsigned)N) {
            atomicAdd(&cnt[d], 1);
            atomicAdd(&cntw[(s >> WSHIFT) * N + d], 1);
        }
    }
}

__global__ void dinv_kernel(const int* __restrict__ cnt, float* __restrict__ dinv, int n) {
    int i = blockIdx.x * blockDim.x + threadIdx.x;
    if (i < n) {
        float deg = (float)(cnt[i] + 1);   // +1 self loop
        dinv[i] = rsqrtf(deg);
    }
}

// two-level scan
__global__ __launch_bounds__(1024) void scanA_kernel(const int* __restrict__ cnt,
        int* __restrict__ offs, int* __restrict__ bsum, int n) {
    __shared__ int buf[1024];
    int tid = threadIdx.x;
    int i = blockIdx.x * 1024 + tid;
    int v = (i < n) ? cnt[i] : 0;
    buf[tid] = v;
    __syncthreads();
    for (int off = 1; off < 1024; off <<= 1) {
        int t = (tid >= off) ? buf[tid - off] : 0;
        __syncthreads();
        buf[tid] += t;
        __syncthreads();
    }
    if (i < n) offs[i] = buf[tid] - v;
    if (tid == 1023) bsum[blockIdx.x] = buf[1023];
}

__global__ __launch_bounds__(1024) void scanB_kernel(int* __restrict__ bsum, int nb) {
    __shared__ int buf[1024];
    int tid = threadIdx.x;
    int v = (tid < nb) ? bsum[tid] : 0;
    buf[tid] = v;
    __syncthreads();
    for (int off = 1; off < 1024; off <<= 1) {
        int t = (tid >= off) ? buf[tid - off] : 0;
        __syncthreads();
        buf[tid] += t;
        __syncthreads();
    }
    if (tid < nb) bsum[tid] = buf[tid] - v;
    if (tid == nb - 1) bsum[nb] = buf[tid];
}

__global__ __launch_bounds__(1024) void scanC_kernel(int* __restrict__ offs,
        const int* __restrict__ bsum, int n, int nb) {
    int i = blockIdx.x * 1024 + threadIdx.x;
    if (i < n) offs[i] += bsum[i >> 10];
    if (i == 0) offs[n] = bsum[nb];
}

// per-row windowed cursors: cur[w][d] = offs[d] + sum_{w'<w} cntw[w'][d]
__global__ void initcur_kernel(const int* __restrict__ offs, const int* __restrict__ cntw,
                               int* __restrict__ cur, int N) {
    int d = blockIdx.x * blockDim.x + threadIdx.x;
    if (d < N) {
        int run = offs[d];
        #pragma unroll
        for (int w = 0; w < NWIN; w++) {
            cur[w * N + d] = run;
            run += cntw[w * N + d];
        }
    }
}

// windowed fill: edges land in their row segment ordered by src window
__global__ void fillw_kernel(const int* __restrict__ src, const int* __restrict__ dst,
                             int* __restrict__ cur, const float* __restrict__ dinv,
                             int2* __restrict__ pack, int E, int N) {
    int e = blockIdx.x * blockDim.x + threadIdx.x;
    if (e < E) {
        int s = src[e], d = dst[e];
        if ((unsigned)s < (unsigned)N && (unsigned)d < (unsigned)N) {
            int w = s >> WSHIFT;
            int j = atomicAdd(&cur[w * N + d], 1);
            if ((unsigned)j < (unsigned)E)
                pack[j] = make_int2(s, __float_as_int(dinv[s] * dinv[d]));
        }
    }
}

// ---------------- lin1: h0 = relu(x @ W1 + b1) ----------------
// BM=32, register-prefetch double buffer; outputs fp32 x0 + fp16 h0.

__global__ __launch_bounds__(256) void lin1_kernel(const float* __restrict__ x,
        const float* __restrict__ W, const float* __restrict__ b,
        float* __restrict__ out32, unsigned short* __restrict__ out16, int n) {
    const int BM = 32, BK = 32;
    __shared__ float As[BM][BK + 1];
    __shared__ float Ws[BK][64];
    int tid = threadIdx.x;
    int row0 = blockIdx.x * BM;
    int tx = tid & 15, ty = tid >> 4;
    float acc[2][4] = {};

    int ar = tid >> 3, ac4 = tid & 7;
    int wr = tid >> 4, wc4 = tid & 15;
    float4 a_pf, w_pf0, w_pf1;

    {
        int row = row0 + ar;
        a_pf = make_float4(0.f, 0.f, 0.f, 0.f);
        if (row < n) a_pf = *(const float4*)&x[(size_t)row * 512 + ac4 * 4];
        w_pf0 = *(const float4*)&W[(size_t)wr * 64 + wc4 * 4];
        w_pf1 = *(const float4*)&W[(size_t)(wr + 16) * 64 + wc4 * 4];
    }

    for (int k0 = 0; k0 < 512; k0 += BK) {
        As[ar][ac4 * 4 + 0] = a_pf.x;
        As[ar][ac4 * 4 + 1] = a_pf.y;
        As[ar][ac4 * 4 + 2] = a_pf.z;
        As[ar][ac4 * 4 + 3] = a_pf.w;
        *(float4*)&Ws[wr][wc4 * 4] = w_pf0;
        *(float4*)&Ws[wr + 16][wc4 * 4] = w_pf1;
        __syncthreads();
        int k1 = k0 + BK;
        if (k1 < 512) {
            int row = row0 + ar;
            a_pf = make_float4(0.f, 0.f, 0.f, 0.f);
            if (row < n) a_pf = *(const float4*)&x[(size_t)row * 512 + k1 + ac4 * 4];
            w_pf0 = *(const float4*)&W[(size_t)(k1 + wr) * 64 + wc4 * 4];
            w_pf1 = *(const float4*)&W[(size_t)(k1 + wr + 16) * 64 + wc4 * 4];
        }
        #pragma unroll
        for (int kk = 0; kk < BK; kk++) {
            float a0 = As[ty * 2 + 0][kk];
            float a1 = As[ty * 2 + 1][kk];
            float4 w = *(float4*)&Ws[kk][tx * 4];
            acc[0][0] += a0 * w.x; acc[0][1] += a0 * w.y; acc[0][2] += a0 * w.z; acc[0][3] += a0 * w.w;
            acc[1][0] += a1 * w.x; acc[1][1] += a1 * w.y; acc[1][2] += a1 * w.z; acc[1][3] += a1 * w.w;
        }
        __syncthreads();
    }
    #pragma unroll
    for (int i = 0; i < 2; i++) {
        int row = row0 + ty * 2 + i;
        if (row < n) {
            #pragma unroll
            for (int j = 0; j < 4; j++) {
                int col = tx * 4 + j;
                float v = fmaxf(acc[i][j] + b[col], 0.f);
                out32[(size_t)row * 64 + col] = v;
                out16[(size_t)row * 64 + col] = f2h(v);
            }
        }
    }
}

// ---------------- fused GCNII layer (code IDENTICAL to R12) ----------------
// 4 waves/block, 8 nodes/wave (8 groups x 8 lanes, uint4 = 8 fp16 per lane).
// W' = beta*W + (1-beta)*I in LDS; y = relu(z @ W').

__global__ __launch_bounds__(256) void layer_kernel(
        const uint4* __restrict__ h16, const float4* __restrict__ x04,
        unsigned short* __restrict__ h_out,
        const int* __restrict__ rowptr, const int2* __restrict__ pack,
        const float* __restrict__ dinv,
        const float* __restrict__ W, float beta, int n) {
    __shared__ float Wsh[HID * HID];          // 16 KB
    __shared__ float zt[4][HID][8];           // 8 KB
    int tid = threadIdx.x;
    float omb = 1.0f - beta;
    for (int i = tid; i < HID * HID; i += 256) {
        int k = i >> 6, cc = i & 63;
        Wsh[i] = beta * W[i] + ((k == cc) ? omb : 0.f);
    }
    __syncthreads();
    int lane = tid & 63, wave = tid >> 6;
    int g = lane >> 3;
    int c = lane & 7;

#define UNPACK_ACC(v, nv)                                              \
    { float2 q;                                                        \
      q = __half22float2(*(__half2*)&(v).x); acc[0] += (nv) * q.x; acc[1] += (nv) * q.y; \
      q = __half22float2(*(__half2*)&(v).y); acc[2] += (nv) * q.x; acc[3] += (nv) * q.y; \
      q = __half22float2(*(__half2*)&(v).z); acc[4] += (nv) * q.x; acc[5] += (nv) * q.y; \
      q = __half22float2(*(__half2*)&(v).w); acc[6] += (nv) * q.x; acc[7] += (nv) * q.y; }

    for (int base = (blockIdx.x * 4 + wave) * 8; base < n; base += gridDim.x * 32) {
        int node = base + g;
        float acc[8] = {0.f, 0.f, 0.f, 0.f, 0.f, 0.f, 0.f, 0.f};
        if (node < n) {
            float di = dinv[node];
            float d2 = di * di;
            uint4 sv = h16[(size_t)node * 8 + c];
            UNPACK_ACC(sv, d2);
            int e0 = rowptr[node];
            int deg = rowptr[node + 1] - e0;
            int e = 0;
            for (; e + 4 <= deg; e += 4) {
                int2 p0 = pack[e0 + e + 0];
                int2 p1 = pack[e0 + e + 1];
                int2 p2 = pack[e0 + e + 2];
                int2 p3 = pack[e0 + e + 3];
                uint4 v0 = h16[(size_t)p0.x * 8 + c];
                uint4 v1 = h16[(size_t)p1.x * 8 + c];
                uint4 v2 = h16[(size_t)p2.x * 8 + c];
                uint4 v3 = h16[(size_t)p3.x * 8 + c];
                float n0 = __int_as_float(p0.y), n1 = __int_as_float(p1.y);
                float n2 = __int_as_float(p2.y), n3 = __int_as_float(p3.y);
                UNPACK_ACC(v0, n0);
                UNPACK_ACC(v1, n1);
                UNPACK_ACC(v2, n2);
                UNPACK_ACC(v3, n3);
            }
            for (; e < deg; e++) {
                int2 p = pack[e0 + e];
                uint4 v = h16[(size_t)p.x * 8 + c];
                float nv = __int_as_float(p.y);
                UNPACK_ACC(v, nv);
            }
            float4 xa = x04[(size_t)node * 16 + 2 * c];
            float4 xb = x04[(size_t)node * 16 + 2 * c + 1];
            acc[0] = 0.5f * acc[0] + 0.5f * xa.x;
            acc[1] = 0.5f * acc[1] + 0.5f * xa.y;
            acc[2] = 0.5f * acc[2] + 0.5f * xa.z;
            acc[3] = 0.5f * acc[3] + 0.5f * xa.w;
            acc[4] = 0.5f * acc[4] + 0.5f * xb.x;
            acc[5] = 0.5f * acc[5] + 0.5f * xb.y;
            acc[6] = 0.5f * acc[6] + 0.5f * xb.z;
            acc[7] = 0.5f * acc[7] + 0.5f * xb.w;
        }
        #pragma unroll
        for (int j = 0; j < 8; j++)
            zt[wave][c * 8 + j][g] = acc[j];
        float mv[8] = {0.f, 0.f, 0.f, 0.f, 0.f, 0.f, 0.f, 0.f};
        #pragma unroll 4
        for (int k = 0; k < HID; k++) {
            float4 zA = *(float4*)&zt[wave][k][0];
            float4 zB = *(float4*)&zt[wave][k][4];
            float wk = Wsh[k * HID + lane];
            mv[0] += zA.x * wk; mv[1] += zA.y * wk;
            mv[2] += zA.z * wk; mv[3] += zA.w * wk;
            mv[4] += zB.x * wk; mv[5] += zB.y * wk;
            mv[6] += zB.z * wk; mv[7] += zB.w * wk;
        }
        #pragma unroll
        for (int j = 0; j < 8; j++) {
            int row = base + j;
            if (row < n)
                h_out[(size_t)row * HID + lane] = f2h(fmaxf(mv[j], 0.f));
        }
    }
#undef UNPACK_ACC
}

// ---------------- lin2 + log_softmax ----------------

__global__ __launch_bounds__(256) void out_kernel(const unsigned short* __restrict__ h,
        const float* __restrict__ W2, const float* __restrict__ b2,
        float* __restrict__ out, int n) {
    __shared__ float W2s[64 * 40];
    alignas(16) __shared__ float hs[4][64];
    int tid = threadIdx.x;
    for (int i = tid; i < 64 * 40; i += 256) W2s[i] = W2[i];
    __syncthreads();
    int lane = tid & 63, wave = tid >> 6;
    int c = (lane < 40) ? lane : 0;
    float wc[64];
    #pragma unroll
    for (int k = 0; k < 64; k++) wc[k] = W2s[k * 40 + c];
    float bias = b2[c];
    for (int i = blockIdx.x * 4 + wave; i < n; i += gridDim.x * 4) {
        hs[wave][lane] = h2f(h[(size_t)i * 64 + lane]);
        float o = bias;
        #pragma unroll
        for (int k4 = 0; k4 < 16; k4++) {
            float4 hb = *(float4*)&hs[wave][k4 * 4];
            o += hb.x * wc[k4 * 4 + 0] + hb.y * wc[k4 * 4 + 1]
               + hb.z * wc[k4 * 4 + 2] + hb.w * wc[k4 * 4 + 3];
        }
        float val = (lane < 40) ? o : -INFINITY;
        float m = val;
        #pragma unroll
        for (int d = 1; d < 64; d <<= 1) m = fmaxf(m, __shfl_xor(m, d, 64));
        float e = (lane < 40) ? expf(o - m) : 0.f;
        float s = e;
        #pragma unroll
        for (int d = 1; d < 64; d <<= 1) s += __shfl_xor(s, d, 64);
        if (lane < 40) out[(size_t)i * 40 + lane] = (o - m) - logf(s);
    }
}

__global__ void zero_out_kernel(float* __restrict__ out, int n) {
    int i = blockIdx.x * blockDim.x + threadIdx.x;
    if (i < n) out[i] = 0.f;
}

// ---------------- launcher ----------------

extern "C" void kernel_launch(void* const* d_in, const int* in_sizes, int n_in,
                              void* d_out, int out_size, void* d_ws, size_t ws_size,
                              hipStream_t stream) {
    const float* x    = (const float*)d_in[0];
    const int*   ei   = (const int*)d_in[1];     // int32
    const float* W1   = (const float*)d_in[2];
    const float* b1   = (const float*)d_in[3];
    const float* Wc   = (const float*)d_in[4];
    const float* W2   = (const float*)d_in[5];
    const float* b2   = (const float*)d_in[6];
    float* outp = (float*)d_out;

    const int N = in_sizes[0] / 512;         // 50000
    const int E = in_sizes[1] / 2;           // 800000
    const int L = in_sizes[4] / (HID * HID); // 64

    const int* src = ei;
    const int* dst = ei + E;
    const int NB_SCAN = (N + 1023) / 1024;   // 49

    size_t need = (size_t)N * HID * 4                 // x0b fp32
                + (size_t)N * HID * 2 * 2             // hA16, hB16
                + ((size_t)N * 2 + (N + 1) + (NB_SCAN + 1)) * 4   // dinv, cnt, offs, bsum
                + (size_t)N * NWIN * 4 * 2            // cntw, cur
                + (size_t)E * 8;                      // pack
    if (ws_size < need) {
        zero_out_kernel<<<(out_size + 255) / 256, 256, 0, stream>>>(outp, out_size);
        return;
    }
    char* p = (char*)d_ws;
    float* x0b  = (float*)p;               p += (size_t)N * HID * 4;
    unsigned short* hA16 = (unsigned short*)p;  p += (size_t)N * HID * 2;
    unsigned short* hB16 = (unsigned short*)p;  p += (size_t)N * HID * 2;
    float* dinv = (float*)p;               p += (size_t)N * 4;
    int2*  pack = (int2*)p;                p += (size_t)E * 8;
    int*   cnt  = (int*)p;                 p += (size_t)N * 4;
    int*   offs = (int*)p;                 p += (size_t)(N + 1) * 4;
    int*   cntw = (int*)p;                 p += (size_t)N * NWIN * 4;
    int*   cur  = (int*)p;                 p += (size_t)N * NWIN * 4;
    int*   bsum = (int*)p;                 p += (size_t)(NB_SCAN + 1) * 4;

    hipMemsetAsync(cnt, 0, (size_t)N * 4, stream);
    hipMemsetAsync(cntw, 0, (size_t)N * NWIN * 4, stream);

    count_kernel<<<(E + 255) / 256, 256, 0, stream>>>(src, dst, cnt, cntw, E, N);
    dinv_kernel<<<(N + 255) / 256, 256, 0, stream>>>(cnt, dinv, N);
    scanA_kernel<<<NB_SCAN, 1024, 0, stream>>>(cnt, offs, bsum, N);
    scanB_kernel<<<1, 1024, 0, stream>>>(bsum, NB_SCAN);
    scanC_kernel<<<NB_SCAN, 1024, 0, stream>>>(offs, bsum, N, NB_SCAN);
    initcur_kernel<<<(N + 255) / 256, 256, 0, stream>>>(offs, cntw, cur, N);
    fillw_kernel<<<(E + 255) / 256, 256, 0, stream>>>(src, dst, cur, dinv, pack, E, N);

    lin1_kernel<<<(N + 31) / 32, 256, 0, stream>>>(x, W1, b1, x0b, hA16, N);

    int nblocks = (N + 31) / 32;            // 1563 blocks, all co-resident
    unsigned short* cur_in = hA16;
    unsigned short* cur_out = hB16;
    for (int l = 0; l < L; l++) {
        float beta = log1pf(1.0f / (float)(l + 1));
        layer_kernel<<<nblocks, 256, 0, stream>>>((const uint4*)cur_in, (const float4*)x0b,
                                                  cur_out, offs, pack, dinv,
                                                  Wc + (size_t)l * HID * HID, beta, N);
        unsigned short* nxt = cur_in;
        cur_in = cur_out;
        cur_out = nxt;
    }

    out_kernel<<<1024, 256, 0, stream>>>(cur_in, W2, b2, outp, N);
}

// Round 14
// 2160.657 us; speedup vs baseline: 1.0215x; 1.0043x over previous
//
#include <hip/hip_runtime.h>
#include <hip/hip_bf16.h>
#include <hip/hip_fp16.h>
#include <math.h>

#define HID 64
#define NWIN 7
#define WSHIFT 13

union HU { __half h; unsigned short u; };
__device__ inline unsigned short f2h(float f) { HU x; x.h = __float2half(f); return x.u; }
__device__ inline float h2f(unsigned short u) { HU x; x.u = u; return __half2float(x.h); }

// ---------------- CSR build (windowed, unchanged from R13) ----------------

__global__ void count_kernel(const int* __restrict__ src, const int* __restrict__ dst,
                             int* __restrict__ cnt, int* __restrict__ cntw, int E, int N) {
    int e = blockIdx.x * blockDim.x + threadIdx.x;
    if (e < E) {
        int s = src[e], d = dst[e];
        if ((unsigned)s < (unsigned)N && (unsigned)d < (unsigned)N) {
            atomicAdd(&cnt[d], 1);
            atomicAdd(&cntw[(s >> WSHIFT) * N + d], 1);
        }
    }
}

__global__ void dinv_kernel(const int* __restrict__ cnt, float* __restrict__ dinv, int n) {
    int i = blockIdx.x * blockDim.x + threadIdx.x;
    if (i < n) {
        float deg = (float)(cnt[i] + 1);
        dinv[i] = rsqrtf(deg);
    }
}

__global__ __launch_bounds__(1024) void scanA_kernel(const int* __restrict__ cnt,
        int* __restrict__ offs, int* __restrict__ bsum, int n) {
    __shared__ int buf[1024];
    int tid = threadIdx.x;
    int i = blockIdx.x * 1024 + tid;
    int v = (i < n) ? cnt[i] : 0;
    buf[tid] = v;
    __syncthreads();
    for (int off = 1; off < 1024; off <<= 1) {
        int t = (tid >= off) ? buf[tid - off] : 0;
        __syncthreads();
        buf[tid] += t;
        __syncthreads();
    }
    if (i < n) offs[i] = buf[tid] - v;
    if (tid == 1023) bsum[blockIdx.x] = buf[1023];
}

__global__ __launch_bounds__(1024) void scanB_kernel(int* __restrict__ bsum, int nb) {
    __shared__ int buf[1024];
    int tid = threadIdx.x;
    int v = (tid < nb) ? bsum[tid] : 0;
    buf[tid] = v;
    __syncthreads();
    for (int off = 1; off < 1024; off <<= 1) {
        int t = (tid >= off) ? buf[tid - off] : 0;
        __syncthreads();
        buf[tid] += t;
        __syncthreads();
    }
    if (tid < nb) bsum[tid] = buf[tid] - v;
    if (tid == nb - 1) bsum[nb] = buf[tid];
}

__global__ __launch_bounds__(1024) void scanC_kernel(int* __restrict__ offs,
        const int* __restrict__ bsum, int n, int nb) {
    int i = blockIdx.x * 1024 + threadIdx.x;
    if (i < n) offs[i] += bsum[i >> 10];
    if (i == 0) offs[n] = bsum[nb];
}

__global__ void initcur_kernel(const int* __restrict__ offs, const int* __restrict__ cntw,
                               int* __restrict__ cur, int N) {
    int d = blockIdx.x * blockDim.x + threadIdx.x;
    if (d < N) {
        int run = offs[d];
        #pragma unroll
        for (int w = 0; w < NWIN; w++) {
            cur[w * N + d] = run;
            run += cntw[w * N + d];
        }
    }
}

__global__ void fillw_kernel(const int* __restrict__ src, const int* __restrict__ dst,
                             int* __restrict__ cur, const float* __restrict__ dinv,
                             int2* __restrict__ pack, int E, int N) {
    int e = blockIdx.x * blockDim.x + threadIdx.x;
    if (e < E) {
        int s = src[e], d = dst[e];
        if ((unsigned)s < (unsigned)N && (unsigned)d < (unsigned)N) {
            int w = s >> WSHIFT;
            int j = atomicAdd(&cur[w * N + d], 1);
            if ((unsigned)j < (unsigned)E)
                pack[j] = make_int2(s, __float_as_int(dinv[s] * dinv[d]));
        }
    }
}

// ---------------- lin1 (unchanged from R13) ----------------

__global__ __launch_bounds__(256) void lin1_kernel(const float* __restrict__ x,
        const float* __restrict__ W, const float* __restrict__ b,
        float* __restrict__ out32, unsigned short* __restrict__ out16, int n) {
    const int BM = 32, BK = 32;
    __shared__ float As[BM][BK + 1];
    __shared__ float Ws[BK][64];
    int tid = threadIdx.x;
    int row0 = blockIdx.x * BM;
    int tx = tid & 15, ty = tid >> 4;
    float acc[2][4] = {};

    int ar = tid >> 3, ac4 = tid & 7;
    int wr = tid >> 4, wc4 = tid & 15;
    float4 a_pf, w_pf0, w_pf1;

    {
        int row = row0 + ar;
        a_pf = make_float4(0.f, 0.f, 0.f, 0.f);
        if (row < n) a_pf = *(const float4*)&x[(size_t)row * 512 + ac4 * 4];
        w_pf0 = *(const float4*)&W[(size_t)wr * 64 + wc4 * 4];
        w_pf1 = *(const float4*)&W[(size_t)(wr + 16) * 64 + wc4 * 4];
    }

    for (int k0 = 0; k0 < 512; k0 += BK) {
        As[ar][ac4 * 4 + 0] = a_pf.x;
        As[ar][ac4 * 4 + 1] = a_pf.y;
        As[ar][ac4 * 4 + 2] = a_pf.z;
        As[ar][ac4 * 4 + 3] = a_pf.w;
        *(float4*)&Ws[wr][wc4 * 4] = w_pf0;
        *(float4*)&Ws[wr + 16][wc4 * 4] = w_pf1;
        __syncthreads();
        int k1 = k0 + BK;
        if (k1 < 512) {
            int row = row0 + ar;
            a_pf = make_float4(0.f, 0.f, 0.f, 0.f);
            if (row < n) a_pf = *(const float4*)&x[(size_t)row * 512 + k1 + ac4 * 4];
            w_pf0 = *(const float4*)&W[(size_t)(k1 + wr) * 64 + wc4 * 4];
            w_pf1 = *(const float4*)&W[(size_t)(k1 + wr + 16) * 64 + wc4 * 4];
        }
        #pragma unroll
        for (int kk = 0; kk < BK; kk++) {
            float a0 = As[ty * 2 + 0][kk];
            float a1 = As[ty * 2 + 1][kk];
            float4 w = *(float4*)&Ws[kk][tx * 4];
            acc[0][0] += a0 * w.x; acc[0][1] += a0 * w.y; acc[0][2] += a0 * w.z; acc[0][3] += a0 * w.w;
            acc[1][0] += a1 * w.x; acc[1][1] += a1 * w.y; acc[1][2] += a1 * w.z; acc[1][3] += a1 * w.w;
        }
        __syncthreads();
    }
    #pragma unroll
    for (int i = 0; i < 2; i++) {
        int row = row0 + ty * 2 + i;
        if (row < n) {
            #pragma unroll
            for (int j = 0; j < 4; j++) {
                int col = tx * 4 + j;
                float v = fmaxf(acc[i][j] + b[col], 0.f);
                out32[(size_t)row * 64 + col] = v;
                out16[(size_t)row * 64 + col] = f2h(v);
            }
        }
    }
}

// ---------------- fused GCNII layer: software-pipelined pack prefetch ----------------
// 4 waves/block, 8 nodes/wave (8 groups x 8 lanes, uint4 = 8 fp16 per lane).
// Steady state: row loads of chunk i overlap pack loads of chunk i+1 and FMA of chunk i.
// x0/self loads hoisted before the edge loop. W' = beta*W + (1-beta)*I in LDS.

__global__ __launch_bounds__(256) void layer_kernel(
        const uint4* __restrict__ h16, const float4* __restrict__ x04,
        unsigned short* __restrict__ h_out,
        const int* __restrict__ rowptr, const int2* __restrict__ pack,
        const float* __restrict__ dinv,
        const float* __restrict__ W, float beta, int n) {
    __shared__ float Wsh[HID * HID];          // 16 KB
    __shared__ float zt[4][HID][8];           // 8 KB
    int tid = threadIdx.x;
    float omb = 1.0f - beta;
    for (int i = tid; i < HID * HID; i += 256) {
        int k = i >> 6, cc = i & 63;
        Wsh[i] = beta * W[i] + ((k == cc) ? omb : 0.f);
    }
    __syncthreads();
    int lane = tid & 63, wave = tid >> 6;
    int g = lane >> 3;
    int c = lane & 7;

#define UNPACK_ACC(v, nv)                                              \
    { float2 q;                                                        \
      q = __half22float2(*(__half2*)&(v).x); acc[0] += (nv) * q.x; acc[1] += (nv) * q.y; \
      q = __half22float2(*(__half2*)&(v).y); acc[2] += (nv) * q.x; acc[3] += (nv) * q.y; \
      q = __half22float2(*(__half2*)&(v).z); acc[4] += (nv) * q.x; acc[5] += (nv) * q.y; \
      q = __half22float2(*(__half2*)&(v).w); acc[6] += (nv) * q.x; acc[7] += (nv) * q.y; }

    for (int base = (blockIdx.x * 4 + wave) * 8; base < n; base += gridDim.x * 32) {
        int node = base + g;
        float acc[8] = {0.f, 0.f, 0.f, 0.f, 0.f, 0.f, 0.f, 0.f};
        if (node < n) {
            // hoist all node-level loads: issue early, consume late
            float di = dinv[node];
            uint4 sv = h16[(size_t)node * 8 + c];
            float4 xa = x04[(size_t)node * 16 + 2 * c];
            float4 xb = x04[(size_t)node * 16 + 2 * c + 1];
            int e0 = rowptr[node];
            int deg = rowptr[node + 1] - e0;
            float d2 = di * di;
            UNPACK_ACC(sv, d2);

            int e = 0;
            if (deg >= 4) {
                // prologue: packs for chunk 0
                int2 pp0 = pack[e0 + 0];
                int2 pp1 = pack[e0 + 1];
                int2 pp2 = pack[e0 + 2];
                int2 pp3 = pack[e0 + 3];
                for (; e + 8 <= deg; e += 4) {
                    // rows for current chunk (depend on pp)
                    uint4 v0 = h16[(size_t)pp0.x * 8 + c];
                    uint4 v1 = h16[(size_t)pp1.x * 8 + c];
                    uint4 v2 = h16[(size_t)pp2.x * 8 + c];
                    uint4 v3 = h16[(size_t)pp3.x * 8 + c];
                    // prefetch next chunk's packs (independent -> stay in flight during FMA)
                    int2 np0 = pack[e0 + e + 4];
                    int2 np1 = pack[e0 + e + 5];
                    int2 np2 = pack[e0 + e + 6];
                    int2 np3 = pack[e0 + e + 7];
                    float n0 = __int_as_float(pp0.y), n1 = __int_as_float(pp1.y);
                    float n2 = __int_as_float(pp2.y), n3 = __int_as_float(pp3.y);
                    UNPACK_ACC(v0, n0);
                    UNPACK_ACC(v1, n1);
                    UNPACK_ACC(v2, n2);
                    UNPACK_ACC(v3, n3);
                    pp0 = np0; pp1 = np1; pp2 = np2; pp3 = np3;
                }
                // epilogue: last full chunk held in pp (valid: e+4 <= deg)
                {
                    uint4 v0 = h16[(size_t)pp0.x * 8 + c];
                    uint4 v1 = h16[(size_t)pp1.x * 8 + c];
                    uint4 v2 = h16[(size_t)pp2.x * 8 + c];
                    uint4 v3 = h16[(size_t)pp3.x * 8 + c];
                    float n0 = __int_as_float(pp0.y), n1 = __int_as_float(pp1.y);
                    float n2 = __int_as_float(pp2.y), n3 = __int_as_float(pp3.y);
                    UNPACK_ACC(v0, n0);
                    UNPACK_ACC(v1, n1);
                    UNPACK_ACC(v2, n2);
                    UNPACK_ACC(v3, n3);
                    e += 4;
                }
            }
            for (; e < deg; e++) {
                int2 p = pack[e0 + e];
                uint4 v = h16[(size_t)p.x * 8 + c];
                float nv = __int_as_float(p.y);
                UNPACK_ACC(v, nv);
            }
            // z = 0.5*agg + 0.5*x0 (x0 loads issued long ago)
            acc[0] = 0.5f * acc[0] + 0.5f * xa.x;
            acc[1] = 0.5f * acc[1] + 0.5f * xa.y;
            acc[2] = 0.5f * acc[2] + 0.5f * xa.z;
            acc[3] = 0.5f * acc[3] + 0.5f * xa.w;
            acc[4] = 0.5f * acc[4] + 0.5f * xb.x;
            acc[5] = 0.5f * acc[5] + 0.5f * xb.y;
            acc[6] = 0.5f * acc[6] + 0.5f * xb.z;
            acc[7] = 0.5f * acc[7] + 0.5f * xb.w;
        }
        // ---- transpose z into zt[k][node] ----
        #pragma unroll
        for (int j = 0; j < 8; j++)
            zt[wave][c * 8 + j][g] = acc[j];
        // ---- phase 2: y = z @ W' for 8 nodes ----
        float mv[8] = {0.f, 0.f, 0.f, 0.f, 0.f, 0.f, 0.f, 0.f};
        #pragma unroll 4
        for (int k = 0; k < HID; k++) {
            float4 zA = *(float4*)&zt[wave][k][0];
            float4 zB = *(float4*)&zt[wave][k][4];
            float wk = Wsh[k * HID + lane];
            mv[0] += zA.x * wk; mv[1] += zA.y * wk;
            mv[2] += zA.z * wk; mv[3] += zA.w * wk;
            mv[4] += zB.x * wk; mv[5] += zB.y * wk;
            mv[6] += zB.z * wk; mv[7] += zB.w * wk;
        }
        #pragma unroll
        for (int j = 0; j < 8; j++) {
            int row = base + j;
            if (row < n)
                h_out[(size_t)row * HID + lane] = f2h(fmaxf(mv[j], 0.f));
        }
    }
#undef UNPACK_ACC
}

// ---------------- lin2 + log_softmax (unchanged) ----------------

__global__ __launch_bounds__(256) void out_kernel(const unsigned short* __restrict__ h,
        const float* __restrict__ W2, const float* __restrict__ b2,
        float* __restrict__ out, int n) {
    __shared__ float W2s[64 * 40];
    alignas(16) __shared__ float hs[4][64];
    int tid = threadIdx.x;
    for (int i = tid; i < 64 * 40; i += 256) W2s[i] = W2[i];
    __syncthreads();
    int lane = tid & 63, wave = tid >> 6;
    int c = (lane < 40) ? lane : 0;
    float wc[64];
    #pragma unroll
    for (int k = 0; k < 64; k++) wc[k] = W2s[k * 40 + c];
    float bias = b2[c];
    for (int i = blockIdx.x * 4 + wave; i < n; i += gridDim.x * 4) {
        hs[wave][lane] = h2f(h[(size_t)i * 64 + lane]);
        float o = bias;
        #pragma unroll
        for (int k4 = 0; k4 < 16; k4++) {
            float4 hb = *(float4*)&hs[wave][k4 * 4];
            o += hb.x * wc[k4 * 4 + 0] + hb.y * wc[k4 * 4 + 1]
               + hb.z * wc[k4 * 4 + 2] + hb.w * wc[k4 * 4 + 3];
        }
        float val = (lane < 40) ? o : -INFINITY;
        float m = val;
        #pragma unroll
        for (int d = 1; d < 64; d <<= 1) m = fmaxf(m, __shfl_xor(m, d, 64));
        float e = (lane < 40) ? expf(o - m) : 0.f;
        float s = e;
        #pragma unroll
        for (int d = 1; d < 64; d <<= 1) s += __shfl_xor(s, d, 64);
        if (lane < 40) out[(size_t)i * 40 + lane] = (o - m) - logf(s);
    }
}

__global__ void zero_out_kernel(float* __restrict__ out, int n) {
    int i = blockIdx.x * blockDim.x + threadIdx.x;
    if (i < n) out[i] = 0.f;
}

// ---------------- launcher ----------------

extern "C" void kernel_launch(void* const* d_in, const int* in_sizes, int n_in,
                              void* d_out, int out_size, void* d_ws, size_t ws_size,
                              hipStream_t stream) {
    const float* x    = (const float*)d_in[0];
    const int*   ei   = (const int*)d_in[1];     // int32
    const float* W1   = (const float*)d_in[2];
    const float* b1   = (const float*)d_in[3];
    const float* Wc   = (const float*)d_in[4];
    const float* W2   = (const float*)d_in[5];
    const float* b2   = (const float*)d_in[6];
    float* outp = (float*)d_out;

    const int N = in_sizes[0] / 512;
    const int E = in_sizes[1] / 2;
    const int L = in_sizes[4] / (HID * HID);

    const int* src = ei;
    const int* dst = ei + E;
    const int NB_SCAN = (N + 1023) / 1024;

    size_t need = (size_t)N * HID * 4
                + (size_t)N * HID * 2 * 2
                + ((size_t)N * 2 + (N + 1) + (NB_SCAN + 1)) * 4
                + (size_t)N * NWIN * 4 * 2
                + (size_t)E * 8;
    if (ws_size < need) {
        zero_out_kernel<<<(out_size + 255) / 256, 256, 0, stream>>>(outp, out_size);
        return;
    }
    char* p = (char*)d_ws;
    float* x0b  = (float*)p;               p += (size_t)N * HID * 4;
    unsigned short* hA16 = (unsigned short*)p;  p += (size_t)N * HID * 2;
    unsigned short* hB16 = (unsigned short*)p;  p += (size_t)N * HID * 2;
    float* dinv = (float*)p;               p += (size_t)N * 4;
    int2*  pack = (int2*)p;                p += (size_t)E * 8;
    int*   cnt  = (int*)p;                 p += (size_t)N * 4;
    int*   offs = (int*)p;                 p += (size_t)(N + 1) * 4;
    int*   cntw = (int*)p;                 p += (size_t)N * NWIN * 4;
    int*   cur  = (int*)p;                 p += (size_t)N * NWIN * 4;
    int*   bsum = (int*)p;                 p += (size_t)(NB_SCAN + 1) * 4;

    hipMemsetAsync(cnt, 0, (size_t)N * 4, stream);
    hipMemsetAsync(cntw, 0, (size_t)N * NWIN * 4, stream);

    count_kernel<<<(E + 255) / 256, 256, 0, stream>>>(src, dst, cnt, cntw, E, N);
    dinv_kernel<<<(N + 255) / 256, 256, 0, stream>>>(cnt, dinv, N);
    scanA_kernel<<<NB_SCAN, 1024, 0, stream>>>(cnt, offs, bsum, N);
    scanB_kernel<<<1, 1024, 0, stream>>>(bsum, NB_SCAN);
    scanC_kernel<<<NB_SCAN, 1024, 0, stream>>>(offs, bsum, N, NB_SCAN);
    initcur_kernel<<<(N + 255) / 256, 256, 0, stream>>>(offs, cntw, cur, N);
    fillw_kernel<<<(E + 255) / 256, 256, 0, stream>>>(src, dst, cur, dinv, pack, E, N);

    lin1_kernel<<<(N + 31) / 32, 256, 0, stream>>>(x, W1, b1, x0b, hA16, N);

    int nblocks = (N + 31) / 32;
    unsigned short* cur_in = hA16;
    unsigned short* cur_out = hB16;
    for (int l = 0; l < L; l++) {
        float beta = log1pf(1.0f / (float)(l + 1));
        layer_kernel<<<nblocks, 256, 0, stream>>>((const uint4*)cur_in, (const float4*)x0b,
                                                  cur_out, offs, pack, dinv,
                                                  Wc + (size_t)l * HID * HID, beta, N);
        unsigned short* nxt = cur_in;
        cur_in = cur_out;
        cur_out = nxt;
    }

    out_kernel<<<1024, 256, 0, stream>>>(cur_in, W2, b2, outp, N);
}